// Round 9
// baseline (390.762 us; speedup 1.0000x reference)
//
#include <hip/hip_runtime.h>
#include <hip/hip_bf16.h>

// N=1024 rois, DF=1024, DK=DV=DG=64, NR=16 heads.
// ws: [0,32MB) w=max(relu(pe@Wg^T+bg),1e-6) f16 [16][1024][1024]
//     [32MB) Q bf16 [16][1024][64]; [34MB) K same; [36MB) Vt bf16 [16][64][1024]; [38MB) Y bf16 [1024][1024]

typedef __bf16 bf16_t;
typedef _Float16 f16_t;
typedef __attribute__((ext_vector_type(8))) __bf16 bf16x8;
typedef __attribute__((ext_vector_type(8))) _Float16 f16x8;
typedef __attribute__((ext_vector_type(4))) float f32x4;

__device__ inline bf16_t f2b(float f) {
    unsigned u = __builtin_bit_cast(unsigned, f);
    unsigned r = u + 0x7fffu + ((u >> 16) & 1u);
    unsigned short h = (unsigned short)(r >> 16);
    return __builtin_bit_cast(bf16_t, h);
}

// ---- fused (g + Q/K/V projections) heterogeneous kernel ----
// blocks [0,768): proj z=bid/256 (0:Q,1:K,2:V), 16x16 tile grid
// blocks [768,768+16384): g, 64 pe-rows per block, LDS-FREE (round-8 lesson:
// LDS transpose + barriers was latency-bound at 2.3 TB/s, 3.1M bank conflicts).
// Quarter-row per lane: lane (r'=t>>2,c'=t&3) owns floats [c'*16,c'*16+16) of
// row r'; 4-lane shfl butterfly completes the dot. No LDS, no barriers.
__global__ __launch_bounds__(256) void fused_g_proj_k(
        const float* __restrict__ pe, const float* __restrict__ Wg, const float* __restrict__ bg,
        f16_t* __restrict__ Wout,
        const float* __restrict__ x,
        const float* __restrict__ Wq, const float* __restrict__ bq, bf16_t* __restrict__ Qb,
        const float* __restrict__ Wk, const float* __restrict__ bk, bf16_t* __restrict__ Kb,
        const float* __restrict__ Wv, const float* __restrict__ bv, bf16_t* __restrict__ Vb) {
    __shared__ bf16_t As[2][64][40];        // proj path only (10 KB)
    __shared__ bf16_t Bs[2][64][40];        // proj path only (10 KB)
    const int bid = blockIdx.x;
    const int t = threadIdx.x;

    if (bid < 768) {
        // ================= projection GEMM: C = x @ W^T + b =================
        const int z = bid >> 8, rem = bid & 255;
        const float* B = (z == 0) ? Wq : (z == 1) ? Wk : Wv;
        const float* bias = (z == 0) ? bq : (z == 1) ? bk : bv;
        bf16_t* outp = (z == 0) ? Qb : (z == 1) ? Kb : Vb;
        const int m0 = (rem >> 4) * 64, n0 = (rem & 15) * 64;
        const int lr = t >> 2, lq = t & 3;

        auto stage = [&](bf16_t (*dst)[64][40], const float* __restrict__ Sp, int row0, int buf, int k0) {
            const float* p = Sp + (long)(row0 + lr) * 1024 + k0 + lq * 8;
            float4 u0 = *(const float4*)p;
            float4 u1 = *(const float4*)(p + 4);
            bf16x8 v;
            v[0] = f2b(u0.x); v[1] = f2b(u0.y); v[2] = f2b(u0.z); v[3] = f2b(u0.w);
            v[4] = f2b(u1.x); v[5] = f2b(u1.y); v[6] = f2b(u1.z); v[7] = f2b(u1.w);
            *(bf16x8*)&dst[buf][lr][lq * 8] = v;
        };

        const int wid = t >> 6, lane = t & 63;
        const int wm = (wid >> 1) * 32, wn = (wid & 1) * 32;
        const int ml = lane & 15, kl = (lane >> 4) * 8;
        f32x4 acc[2][2] = {};

        stage(As, x, m0, 0, 0);
        stage(Bs, B, n0, 0, 0);
        __syncthreads();
        for (int kt = 0; kt < 32; kt++) {
            const int buf = kt & 1;
            if (kt + 1 < 32) { stage(As, x, m0, buf ^ 1, (kt + 1) * 32); stage(Bs, B, n0, buf ^ 1, (kt + 1) * 32); }
            bf16x8 a0 = *(const bf16x8*)&As[buf][wm + ml][kl];
            bf16x8 a1 = *(const bf16x8*)&As[buf][wm + 16 + ml][kl];
            bf16x8 b0 = *(const bf16x8*)&Bs[buf][wn + ml][kl];
            bf16x8 b1 = *(const bf16x8*)&Bs[buf][wn + 16 + ml][kl];
            acc[0][0] = __builtin_amdgcn_mfma_f32_16x16x32_bf16(a0, b0, acc[0][0], 0, 0, 0);
            acc[0][1] = __builtin_amdgcn_mfma_f32_16x16x32_bf16(a0, b1, acc[0][1], 0, 0, 0);
            acc[1][0] = __builtin_amdgcn_mfma_f32_16x16x32_bf16(a1, b0, acc[1][0], 0, 0, 0);
            acc[1][1] = __builtin_amdgcn_mfma_f32_16x16x32_bf16(a1, b1, acc[1][1], 0, 0, 0);
            __syncthreads();
        }

#pragma unroll
        for (int mt = 0; mt < 2; mt++)
#pragma unroll
            for (int nt = 0; nt < 2; nt++) {
                f32x4 v = acc[mt][nt];
                const int rbase = m0 + wm + mt * 16 + ((lane >> 4) << 2);
                const int col = n0 + wn + nt * 16 + (lane & 15);
#pragma unroll
                for (int r = 0; r < 4; r++) {
                    const int row = rbase + r;
                    float val = v[r] + bias[col];
                    int h = col >> 6, d = col & 63;
                    if (z < 2) outp[((long)h << 16) + ((long)row << 6) + d] = f2b(val);
                    else       outp[((long)h << 16) + ((long)d << 10) + row] = f2b(val);
                }
            }
    } else {
        // ================= g: w = max(relu(pe@Wg^T+bg), 1e-6) =================
        // f32 math (precision cliff at relu boundary — round-2 lesson).
        const long rowbase = (long)(bid - 768) * 64;   // 64 flat pe-rows per block
        const int rr = t >> 2;                         // row within block (0..63)
        const int cq = t & 3;                          // quarter index (0..3)
        const long row = rowbase + rr;

        // load my 16 floats of the pe row (4 x dwordx4, 64B-contiguous per row)
        const float4* pr = (const float4*)(pe + (row << 6) + (cq << 4));
        float4 pv0 = pr[0], pv1 = pr[1], pv2 = pr[2], pv3 = pr[3];

        // 16 head-partials from registers; Wg quarters are L1-hot broadcasts
        float p[16];
#pragma unroll 4
        for (int h = 0; h < 16; h++) {
            const float4* wq = (const float4*)(Wg + (h << 6) + (cq << 4));
            float4 w0 = wq[0], w1 = wq[1], w2 = wq[2], w3 = wq[3];
            float a = pv0.x * w0.x + pv0.y * w0.y + pv0.z * w0.z + pv0.w * w0.w;
            a += pv1.x * w1.x + pv1.y * w1.y + pv1.z * w1.z + pv1.w * w1.w;
            a += pv2.x * w2.x + pv2.y * w2.y + pv2.z * w2.z + pv2.w * w2.w;
            a += pv3.x * w3.x + pv3.y * w3.y + pv3.z * w3.z + pv3.w * w3.w;
            p[h] = a;
        }
        // butterfly over the 4-lane group -> full 64-float dot in every lane
#pragma unroll
        for (int h = 0; h < 16; h++) {
            p[h] += __shfl_xor(p[h], 1);
            p[h] += __shfl_xor(p[h], 2);
        }
        // each lane stores 4 heads: h = cq*4+m (static select tree, no scratch)
        const float4 bg4 = *(const float4*)(bg + (cq << 2));
#pragma unroll
        for (int m = 0; m < 4; m++) {
            float v = (cq & 2) ? ((cq & 1) ? p[12 + m] : p[8 + m])
                               : ((cq & 1) ? p[4 + m]  : p[m]);
            float bv_ = (m == 0) ? bg4.x : (m == 1) ? bg4.y : (m == 2) ? bg4.z : bg4.w;
            // w = max(relu(v+bg),1e-6) == max(v+bg,1e-6); softmax(qk+log w) == w*e^qk/sum
            v = fmaxf(v + bv_, 1e-6f);
            const int h = (cq << 2) + m;
            Wout[((long)h << 20) + rowbase + rr] = (f16_t)v;
        }
    }
}

// ---- final GEMM: out f32 = Yb @ Wy^T + by + x ----
__global__ __launch_bounds__(256) void gemmY_k(const bf16_t* __restrict__ A,
                                               const float* __restrict__ Bw,
                                               const float* __restrict__ bias,
                                               float* __restrict__ outp,
                                               const float* __restrict__ extra) {
    __shared__ bf16_t As[2][64][40];
    __shared__ bf16_t Bs[2][64][40];
    const int t = threadIdx.x;
    const int m0 = blockIdx.y * 64, n0 = blockIdx.x * 64;
    const int lr = t >> 2, lq = t & 3;

    auto stageA = [&](int buf, int k0) {
        const bf16_t* p = A + (long)(m0 + lr) * 1024 + k0 + lq * 8;
        *(bf16x8*)&As[buf][lr][lq * 8] = *(const bf16x8*)p;
    };
    auto stageB = [&](int buf, int k0) {
        const float* p = Bw + (long)(n0 + lr) * 1024 + k0 + lq * 8;
        float4 u0 = *(const float4*)p;
        float4 u1 = *(const float4*)(p + 4);
        bf16x8 v;
        v[0] = f2b(u0.x); v[1] = f2b(u0.y); v[2] = f2b(u0.z); v[3] = f2b(u0.w);
        v[4] = f2b(u1.x); v[5] = f2b(u1.y); v[6] = f2b(u1.z); v[7] = f2b(u1.w);
        *(bf16x8*)&Bs[buf][lr][lq * 8] = v;
    };

    const int wid = t >> 6, lane = t & 63;
    const int wm = (wid >> 1) * 32, wn = (wid & 1) * 32;
    const int ml = lane & 15, kl = (lane >> 4) * 8;
    f32x4 acc[2][2] = {};

    stageA(0, 0);
    stageB(0, 0);
    __syncthreads();
    for (int kt = 0; kt < 32; kt++) {
        const int buf = kt & 1;
        if (kt + 1 < 32) { stageA(buf ^ 1, (kt + 1) * 32); stageB(buf ^ 1, (kt + 1) * 32); }
        bf16x8 a0 = *(const bf16x8*)&As[buf][wm + ml][kl];
        bf16x8 a1 = *(const bf16x8*)&As[buf][wm + 16 + ml][kl];
        bf16x8 b0 = *(const bf16x8*)&Bs[buf][wn + ml][kl];
        bf16x8 b1 = *(const bf16x8*)&Bs[buf][wn + 16 + ml][kl];
        acc[0][0] = __builtin_amdgcn_mfma_f32_16x16x32_bf16(a0, b0, acc[0][0], 0, 0, 0);
        acc[0][1] = __builtin_amdgcn_mfma_f32_16x16x32_bf16(a0, b1, acc[0][1], 0, 0, 0);
        acc[1][0] = __builtin_amdgcn_mfma_f32_16x16x32_bf16(a1, b0, acc[1][0], 0, 0, 0);
        acc[1][1] = __builtin_amdgcn_mfma_f32_16x16x32_bf16(a1, b1, acc[1][1], 0, 0, 0);
        __syncthreads();
    }

#pragma unroll
    for (int mt = 0; mt < 2; mt++)
#pragma unroll
        for (int nt = 0; nt < 2; nt++) {
            f32x4 v = acc[mt][nt];
            const int rbase = m0 + wm + mt * 16 + ((lane >> 4) << 2);
            const int col = n0 + wn + nt * 16 + (lane & 15);
#pragma unroll
            for (int r = 0; r < 4; r++) {
                const int row = rbase + r;
                long idx = ((long)row << 10) + col;
                outp[idx] = v[r] + bias[col] + extra[idx];
            }
        }
}

// ---- fused attention: per (qtile64, head): S=QK^T, p=exp(S)*w, O=pV, O/=sum ----
__global__ __launch_bounds__(256) void attn_kernel(const bf16_t* __restrict__ Q,
                                                   const bf16_t* __restrict__ K,
                                                   const bf16_t* __restrict__ Vt,
                                                   const f16_t* __restrict__ Wf,
                                                   bf16_t* __restrict__ Y) {
    __shared__ bf16_t Qs[64][72];
    __shared__ bf16_t Ks[2][64][72];
    __shared__ bf16_t Vts[2][64][72];
    __shared__ f16_t  Ws[2][64][72];
    __shared__ bf16_t Ps[4][16][72];

    const int qt = blockIdx.x, h = blockIdx.y;
    const int t = threadIdx.x;
    const int w = t >> 6, lane = t & 63;
    const int ml = lane & 15, kq = lane >> 4;
    const int q0 = qt << 6;
    const int sr = t >> 2, sc = (t & 3) << 4;

    const bf16_t* Kh = K + ((long)h << 16);
    const bf16_t* Vh = Vt + ((long)h << 16);
    const f16_t*  Wh = Wf + ((long)h << 20) + ((long)(q0 + sr) << 10);

    {   // stage Q + tile 0
        const bf16_t* src = Q + ((long)h << 16) + ((long)(q0 + sr) << 6) + sc;
        *(bf16x8*)&Qs[sr][sc]     = *(const bf16x8*)src;
        *(bf16x8*)&Qs[sr][sc + 8] = *(const bf16x8*)(src + 8);
        const bf16_t* ks = Kh + ((long)sr << 6) + sc;
        *(bf16x8*)&Ks[0][sr][sc]     = *(const bf16x8*)ks;
        *(bf16x8*)&Ks[0][sr][sc + 8] = *(const bf16x8*)(ks + 8);
        const bf16_t* vs = Vh + ((long)sr << 10) + sc;
        *(bf16x8*)&Vts[0][sr][sc]     = *(const bf16x8*)vs;
        *(bf16x8*)&Vts[0][sr][sc + 8] = *(const bf16x8*)(vs + 8);
        const f16_t* gs = Wh + sc;
        *(f16x8*)&Ws[0][sr][sc]     = *(const f16x8*)gs;
        *(f16x8*)&Ws[0][sr][sc + 8] = *(const f16x8*)(gs + 8);
    }
    __syncthreads();

    const bf16x8 aq0 = *(const bf16x8*)&Qs[(w << 4) + ml][kq * 8];
    const bf16x8 aq1 = *(const bf16x8*)&Qs[(w << 4) + ml][32 + kq * 8];

    f32x4 O[4] = {};
    float lsum[4] = {0.f, 0.f, 0.f, 0.f};

    int buf = 0;
    for (int kt = 0; kt < 16; kt++) {
        bf16x8 rk0, rk1, rv0, rv1;
        f16x8 rw0, rw1;
        const bool pf = (kt < 15);
        if (pf) {  // issue next-tile loads early (T14): latency hides under compute
            const int k0 = (kt + 1) << 6;
            const bf16_t* ks = Kh + ((long)(k0 + sr) << 6) + sc;
            rk0 = *(const bf16x8*)ks; rk1 = *(const bf16x8*)(ks + 8);
            const bf16_t* vs = Vh + ((long)sr << 10) + k0 + sc;
            rv0 = *(const bf16x8*)vs; rv1 = *(const bf16x8*)(vs + 8);
            const f16_t* gs = Wh + k0 + sc;
            rw0 = *(const f16x8*)gs; rw1 = *(const f16x8*)(gs + 8);
        }

        // QK^T: wave tile = 16 q-rows x 64 keys
        f32x4 s[4] = {};
#pragma unroll
        for (int c = 0; c < 4; c++) {
            bf16x8 bk0 = *(const bf16x8*)&Ks[buf][(c << 4) + ml][kq * 8];
            bf16x8 bk1 = *(const bf16x8*)&Ks[buf][(c << 4) + ml][32 + kq * 8];
            s[c] = __builtin_amdgcn_mfma_f32_16x16x32_bf16(aq0, bk0, s[c], 0, 0, 0);
            s[c] = __builtin_amdgcn_mfma_f32_16x16x32_bf16(aq1, bk1, s[c], 0, 0, 0);
        }
        // p = exp(s) * w   (softmax(qk+log w) == w*e^qk/sum; no max needed: |s|<~50)
#pragma unroll
        for (int c = 0; c < 4; c++) {
#pragma unroll
            for (int r = 0; r < 4; r++) {
                float wv = (float)Ws[buf][(w << 4) + (kq << 2) + r][(c << 4) + ml];
                float p = __expf(s[c][r]) * wv;
                lsum[r] += p;
                Ps[w][(kq << 2) + r][(c << 4) + ml] = f2b(p);
            }
        }
        // PV: A = P (per-wave LDS transpose), B = Vt rows (dv)
        const bf16x8 pa0 = *(const bf16x8*)&Ps[w][ml][kq * 8];
        const bf16x8 pa1 = *(const bf16x8*)&Ps[w][ml][32 + kq * 8];
#pragma unroll
        for (int c = 0; c < 4; c++) {
            bf16x8 v0 = *(const bf16x8*)&Vts[buf][(c << 4) + ml][kq * 8];
            bf16x8 v1 = *(const bf16x8*)&Vts[buf][(c << 4) + ml][32 + kq * 8];
            O[c] = __builtin_amdgcn_mfma_f32_16x16x32_bf16(pa0, v0, O[c], 0, 0, 0);
            O[c] = __builtin_amdgcn_mfma_f32_16x16x32_bf16(pa1, v1, O[c], 0, 0, 0);
        }

        if (pf) {  // write-late staging into the other buffer
            const int nb = buf ^ 1;
            *(bf16x8*)&Ks[nb][sr][sc]      = rk0;
            *(bf16x8*)&Ks[nb][sr][sc + 8]  = rk1;
            *(bf16x8*)&Vts[nb][sr][sc]     = rv0;
            *(bf16x8*)&Vts[nb][sr][sc + 8] = rv1;
            *(f16x8*)&Ws[nb][sr][sc]       = rw0;
            *(f16x8*)&Ws[nb][sr][sc + 8]   = rw1;
        }
        __syncthreads();
        buf ^= 1;
    }

#pragma unroll
    for (int r = 0; r < 4; r++) {
        float v = lsum[r];
        v += __shfl_xor(v, 1); v += __shfl_xor(v, 2);
        v += __shfl_xor(v, 4); v += __shfl_xor(v, 8);
        lsum[r] = 1.0f / v;
    }
    const int rowb = q0 + (w << 4) + (kq << 2);
    const int colb = (h << 6) + ml;
#pragma unroll
    for (int c = 0; c < 4; c++)
#pragma unroll
        for (int r = 0; r < 4; r++)
            Y[((long)(rowb + r) << 10) + colb + (c << 4)] = f2b(O[c][r] * lsum[r]);
}

extern "C" void kernel_launch(void* const* d_in, const int* in_sizes, int n_in,
                              void* d_out, int out_size, void* d_ws, size_t ws_size,
                              hipStream_t stream) {
    const float* x  = (const float*)d_in[0];
    const float* pe = (const float*)d_in[1];
    const float* Wq = (const float*)d_in[2];
    const float* bq = (const float*)d_in[3];
    const float* Wk = (const float*)d_in[4];
    const float* bk = (const float*)d_in[5];
    const float* Wv = (const float*)d_in[6];
    const float* bv = (const float*)d_in[7];
    const float* Wg = (const float*)d_in[8];
    const float* bg = (const float*)d_in[9];
    const float* Wy = (const float*)d_in[10];
    const float* by = (const float*)d_in[11];

    char* ws = (char*)d_ws;
    f16_t*  Wf = (f16_t*)ws;                         // 32 MB
    bf16_t* Qb = (bf16_t*)(ws + (32ul << 20));       // 2 MB
    bf16_t* Kb = (bf16_t*)(ws + (34ul << 20));       // 2 MB
    bf16_t* Vb = (bf16_t*)(ws + (36ul << 20));       // 2 MB
    bf16_t* Yb = (bf16_t*)(ws + (38ul << 20));       // 2 MB

    fused_g_proj_k<<<768 + 16384, 256, 0, stream>>>(pe, Wg, bg, Wf,
                                                    x, Wq, bq, Qb, Wk, bk, Kb, Wv, bv, Vb);
    attn_kernel<<<dim3(16, 16), 256, 0, stream>>>(Qb, Kb, Vb, Wf, Yb);
    gemmY_k<<<dim3(16, 16), 256, 0, stream>>>(Yb, Wy, by, (float*)d_out, x);
}

// Round 10
// 142.606 us; speedup vs baseline: 2.7401x; 2.7401x over previous
//
#include <hip/hip_runtime.h>
#include <hip/hip_bf16.h>

// N=1024 rois, DF=1024, DK=DV=DG=64, NR=16 heads.
// ws: [0,32MB) w=max(relu(pe@Wg^T+bg),1e-6) f16 [16][1024][1024]
//     [32MB) Q bf16 [16][1024][64]; [34MB) K same; [36MB) Vt bf16 [16][64][1024]; [38MB) Y bf16 [1024][1024]

typedef __bf16 bf16_t;
typedef _Float16 f16_t;
typedef __attribute__((ext_vector_type(8))) __bf16 bf16x8;
typedef __attribute__((ext_vector_type(8))) _Float16 f16x8;
typedef __attribute__((ext_vector_type(4))) float f32x4;

__device__ inline bf16_t f2b(float f) {
    unsigned u = __builtin_bit_cast(unsigned, f);
    unsigned r = u + 0x7fffu + ((u >> 16) & 1u);
    unsigned short h = (unsigned short)(r >> 16);
    return __builtin_bit_cast(bf16_t, h);
}

// ---- fused (g + Q/K/V projections) heterogeneous kernel ----
// blocks [0,768): proj z=bid/256 (0:Q,1:K,2:V), 16x16 tile grid
// blocks [768,768+4096): g, one thread = one pe row (256 rows/block).
// R8/R9 counter lessons: no LDS, no barriers, no shfl; pv[8] (32 VGPR, no
// spill); Wg/bg lane-uniform -> SGPR s_loads; stores full-wave 128B lines.
__global__ __launch_bounds__(256) void fused_g_proj_k(
        const float* __restrict__ pe, const float* __restrict__ Wg, const float* __restrict__ bg,
        f16_t* __restrict__ Wout,
        const float* __restrict__ x,
        const float* __restrict__ Wq, const float* __restrict__ bq, bf16_t* __restrict__ Qb,
        const float* __restrict__ Wk, const float* __restrict__ bk, bf16_t* __restrict__ Kb,
        const float* __restrict__ Wv, const float* __restrict__ bv, bf16_t* __restrict__ Vb) {
    __shared__ bf16_t As[2][64][40];        // proj path only (10 KB)
    __shared__ bf16_t Bs[2][64][40];        // proj path only (10 KB)
    const int bid = blockIdx.x;
    const int t = threadIdx.x;

    if (bid < 768) {
        // ================= projection GEMM: C = x @ W^T + b =================
        const int z = bid >> 8, rem = bid & 255;
        const float* B = (z == 0) ? Wq : (z == 1) ? Wk : Wv;
        const float* bias = (z == 0) ? bq : (z == 1) ? bk : bv;
        bf16_t* outp = (z == 0) ? Qb : (z == 1) ? Kb : Vb;
        const int m0 = (rem >> 4) * 64, n0 = (rem & 15) * 64;
        const int lr = t >> 2, lq = t & 3;

        auto stage = [&](bf16_t (*dst)[64][40], const float* __restrict__ Sp, int row0, int buf, int k0) {
            const float* p = Sp + (long)(row0 + lr) * 1024 + k0 + lq * 8;
            float4 u0 = *(const float4*)p;
            float4 u1 = *(const float4*)(p + 4);
            bf16x8 v;
            v[0] = f2b(u0.x); v[1] = f2b(u0.y); v[2] = f2b(u0.z); v[3] = f2b(u0.w);
            v[4] = f2b(u1.x); v[5] = f2b(u1.y); v[6] = f2b(u1.z); v[7] = f2b(u1.w);
            *(bf16x8*)&dst[buf][lr][lq * 8] = v;
        };

        const int wid = t >> 6, lane = t & 63;
        const int wm = (wid >> 1) * 32, wn = (wid & 1) * 32;
        const int ml = lane & 15, kl = (lane >> 4) * 8;
        f32x4 acc[2][2] = {};

        stage(As, x, m0, 0, 0);
        stage(Bs, B, n0, 0, 0);
        __syncthreads();
        for (int kt = 0; kt < 32; kt++) {
            const int buf = kt & 1;
            if (kt + 1 < 32) { stage(As, x, m0, buf ^ 1, (kt + 1) * 32); stage(Bs, B, n0, buf ^ 1, (kt + 1) * 32); }
            bf16x8 a0 = *(const bf16x8*)&As[buf][wm + ml][kl];
            bf16x8 a1 = *(const bf16x8*)&As[buf][wm + 16 + ml][kl];
            bf16x8 b0 = *(const bf16x8*)&Bs[buf][wn + ml][kl];
            bf16x8 b1 = *(const bf16x8*)&Bs[buf][wn + 16 + ml][kl];
            acc[0][0] = __builtin_amdgcn_mfma_f32_16x16x32_bf16(a0, b0, acc[0][0], 0, 0, 0);
            acc[0][1] = __builtin_amdgcn_mfma_f32_16x16x32_bf16(a0, b1, acc[0][1], 0, 0, 0);
            acc[1][0] = __builtin_amdgcn_mfma_f32_16x16x32_bf16(a1, b0, acc[1][0], 0, 0, 0);
            acc[1][1] = __builtin_amdgcn_mfma_f32_16x16x32_bf16(a1, b1, acc[1][1], 0, 0, 0);
            __syncthreads();
        }

#pragma unroll
        for (int mt = 0; mt < 2; mt++)
#pragma unroll
            for (int nt = 0; nt < 2; nt++) {
                f32x4 v = acc[mt][nt];
                const int rbase = m0 + wm + mt * 16 + ((lane >> 4) << 2);
                const int col = n0 + wn + nt * 16 + (lane & 15);
#pragma unroll
                for (int r = 0; r < 4; r++) {
                    const int row = rbase + r;
                    float val = v[r] + bias[col];
                    int h = col >> 6, d = col & 63;
                    if (z < 2) outp[((long)h << 16) + ((long)row << 6) + d] = f2b(val);
                    else       outp[((long)h << 16) + ((long)d << 10) + row] = f2b(val);
                }
            }
    } else {
        // ================= g: w = max(relu(pe@Wg^T+bg), 1e-6) =================
        // f32 math (precision cliff at relu boundary — round-2 lesson).
        const long row = (long)(bid - 768) * 256 + t;   // one pe row per thread
        const float4* pr = (const float4*)(pe + (row << 6));

        float p[16];
        float4 pv[8];
        // ---- half 1: floats [0,32) ----
#pragma unroll
        for (int q = 0; q < 8; q++) pv[q] = pr[q];
#pragma unroll
        for (int h = 0; h < 16; h++) {
            const float4* wg4 = (const float4*)(Wg + (h << 6));   // uniform -> s_load
            float a = 0.f;
#pragma unroll
            for (int q = 0; q < 8; q++) {
                float4 w = wg4[q];
                a += pv[q].x * w.x + pv[q].y * w.y + pv[q].z * w.z + pv[q].w * w.w;
            }
            p[h] = a;
        }
        // ---- half 2: floats [32,64) ----
#pragma unroll
        for (int q = 0; q < 8; q++) pv[q] = pr[8 + q];
#pragma unroll
        for (int h = 0; h < 16; h++) {
            const float4* wg4 = (const float4*)(Wg + (h << 6) + 32);
            float a = p[h];
#pragma unroll
            for (int q = 0; q < 8; q++) {
                float4 w = wg4[q];
                a += pv[q].x * w.x + pv[q].y * w.y + pv[q].z * w.z + pv[q].w * w.w;
            }
            a += bg[h];
            // w = max(relu(a),1e-6) == max(a,1e-6); softmax(qk+log w) == w*e^qk/sum
            // store: 64 lanes -> 128B contiguous line per head (R9 lesson)
            Wout[((long)h << 20) + row] = (f16_t)fmaxf(a, 1e-6f);
        }
    }
}

// ---- final GEMM: out f32 = Yb @ Wy^T + by + x ----
__global__ __launch_bounds__(256) void gemmY_k(const bf16_t* __restrict__ A,
                                               const float* __restrict__ Bw,
                                               const float* __restrict__ bias,
                                               float* __restrict__ outp,
                                               const float* __restrict__ extra) {
    __shared__ bf16_t As[2][64][40];
    __shared__ bf16_t Bs[2][64][40];
    const int t = threadIdx.x;
    const int m0 = blockIdx.y * 64, n0 = blockIdx.x * 64;
    const int lr = t >> 2, lq = t & 3;

    auto stageA = [&](int buf, int k0) {
        const bf16_t* p = A + (long)(m0 + lr) * 1024 + k0 + lq * 8;
        *(bf16x8*)&As[buf][lr][lq * 8] = *(const bf16x8*)p;
    };
    auto stageB = [&](int buf, int k0) {
        const float* p = Bw + (long)(n0 + lr) * 1024 + k0 + lq * 8;
        float4 u0 = *(const float4*)p;
        float4 u1 = *(const float4*)(p + 4);
        bf16x8 v;
        v[0] = f2b(u0.x); v[1] = f2b(u0.y); v[2] = f2b(u0.z); v[3] = f2b(u0.w);
        v[4] = f2b(u1.x); v[5] = f2b(u1.y); v[6] = f2b(u1.z); v[7] = f2b(u1.w);
        *(bf16x8*)&Bs[buf][lr][lq * 8] = v;
    };

    const int wid = t >> 6, lane = t & 63;
    const int wm = (wid >> 1) * 32, wn = (wid & 1) * 32;
    const int ml = lane & 15, kl = (lane >> 4) * 8;
    f32x4 acc[2][2] = {};

    stageA(0, 0);
    stageB(0, 0);
    __syncthreads();
    for (int kt = 0; kt < 32; kt++) {
        const int buf = kt & 1;
        if (kt + 1 < 32) { stageA(buf ^ 1, (kt + 1) * 32); stageB(buf ^ 1, (kt + 1) * 32); }
        bf16x8 a0 = *(const bf16x8*)&As[buf][wm + ml][kl];
        bf16x8 a1 = *(const bf16x8*)&As[buf][wm + 16 + ml][kl];
        bf16x8 b0 = *(const bf16x8*)&Bs[buf][wn + ml][kl];
        bf16x8 b1 = *(const bf16x8*)&Bs[buf][wn + 16 + ml][kl];
        acc[0][0] = __builtin_amdgcn_mfma_f32_16x16x32_bf16(a0, b0, acc[0][0], 0, 0, 0);
        acc[0][1] = __builtin_amdgcn_mfma_f32_16x16x32_bf16(a0, b1, acc[0][1], 0, 0, 0);
        acc[1][0] = __builtin_amdgcn_mfma_f32_16x16x32_bf16(a1, b0, acc[1][0], 0, 0, 0);
        acc[1][1] = __builtin_amdgcn_mfma_f32_16x16x32_bf16(a1, b1, acc[1][1], 0, 0, 0);
        __syncthreads();
    }

#pragma unroll
    for (int mt = 0; mt < 2; mt++)
#pragma unroll
        for (int nt = 0; nt < 2; nt++) {
            f32x4 v = acc[mt][nt];
            const int rbase = m0 + wm + mt * 16 + ((lane >> 4) << 2);
            const int col = n0 + wn + nt * 16 + (lane & 15);
#pragma unroll
            for (int r = 0; r < 4; r++) {
                const int row = rbase + r;
                long idx = ((long)row << 10) + col;
                outp[idx] = v[r] + bias[col] + extra[idx];
            }
        }
}

// ---- fused attention: per (qtile64, head): S=QK^T, p=exp(S)*w, O=pV, O/=sum ----
__global__ __launch_bounds__(256) void attn_kernel(const bf16_t* __restrict__ Q,
                                                   const bf16_t* __restrict__ K,
                                                   const bf16_t* __restrict__ Vt,
                                                   const f16_t* __restrict__ Wf,
                                                   bf16_t* __restrict__ Y) {
    __shared__ bf16_t Qs[64][72];
    __shared__ bf16_t Ks[2][64][72];
    __shared__ bf16_t Vts[2][64][72];
    __shared__ f16_t  Ws[2][64][72];
    __shared__ bf16_t Ps[4][16][72];

    const int qt = blockIdx.x, h = blockIdx.y;
    const int t = threadIdx.x;
    const int w = t >> 6, lane = t & 63;
    const int ml = lane & 15, kq = lane >> 4;
    const int q0 = qt << 6;
    const int sr = t >> 2, sc = (t & 3) << 4;

    const bf16_t* Kh = K + ((long)h << 16);
    const bf16_t* Vh = Vt + ((long)h << 16);
    const f16_t*  Wh = Wf + ((long)h << 20) + ((long)(q0 + sr) << 10);

    {   // stage Q + tile 0
        const bf16_t* src = Q + ((long)h << 16) + ((long)(q0 + sr) << 6) + sc;
        *(bf16x8*)&Qs[sr][sc]     = *(const bf16x8*)src;
        *(bf16x8*)&Qs[sr][sc + 8] = *(const bf16x8*)(src + 8);
        const bf16_t* ks = Kh + ((long)sr << 6) + sc;
        *(bf16x8*)&Ks[0][sr][sc]     = *(const bf16x8*)ks;
        *(bf16x8*)&Ks[0][sr][sc + 8] = *(const bf16x8*)(ks + 8);
        const bf16_t* vs = Vh + ((long)sr << 10) + sc;
        *(bf16x8*)&Vts[0][sr][sc]     = *(const bf16x8*)vs;
        *(bf16x8*)&Vts[0][sr][sc + 8] = *(const bf16x8*)(vs + 8);
        const f16_t* gs = Wh + sc;
        *(f16x8*)&Ws[0][sr][sc]     = *(const f16x8*)gs;
        *(f16x8*)&Ws[0][sr][sc + 8] = *(const f16x8*)(gs + 8);
    }
    __syncthreads();

    const bf16x8 aq0 = *(const bf16x8*)&Qs[(w << 4) + ml][kq * 8];
    const bf16x8 aq1 = *(const bf16x8*)&Qs[(w << 4) + ml][32 + kq * 8];

    f32x4 O[4] = {};
    float lsum[4] = {0.f, 0.f, 0.f, 0.f};

    int buf = 0;
    for (int kt = 0; kt < 16; kt++) {
        bf16x8 rk0, rk1, rv0, rv1;
        f16x8 rw0, rw1;
        const bool pf = (kt < 15);
        if (pf) {  // issue next-tile loads early (T14): latency hides under compute
            const int k0 = (kt + 1) << 6;
            const bf16_t* ks = Kh + ((long)(k0 + sr) << 6) + sc;
            rk0 = *(const bf16x8*)ks; rk1 = *(const bf16x8*)(ks + 8);
            const bf16_t* vs = Vh + ((long)sr << 10) + k0 + sc;
            rv0 = *(const bf16x8*)vs; rv1 = *(const bf16x8*)(vs + 8);
            const f16_t* gs = Wh + k0 + sc;
            rw0 = *(const f16x8*)gs; rw1 = *(const f16x8*)(gs + 8);
        }

        // QK^T: wave tile = 16 q-rows x 64 keys
        f32x4 s[4] = {};
#pragma unroll
        for (int c = 0; c < 4; c++) {
            bf16x8 bk0 = *(const bf16x8*)&Ks[buf][(c << 4) + ml][kq * 8];
            bf16x8 bk1 = *(const bf16x8*)&Ks[buf][(c << 4) + ml][32 + kq * 8];
            s[c] = __builtin_amdgcn_mfma_f32_16x16x32_bf16(aq0, bk0, s[c], 0, 0, 0);
            s[c] = __builtin_amdgcn_mfma_f32_16x16x32_bf16(aq1, bk1, s[c], 0, 0, 0);
        }
        // p = exp(s) * w   (softmax(qk+log w) == w*e^qk/sum; no max needed: |s|<~50)
#pragma unroll
        for (int c = 0; c < 4; c++) {
#pragma unroll
            for (int r = 0; r < 4; r++) {
                float wv = (float)Ws[buf][(w << 4) + (kq << 2) + r][(c << 4) + ml];
                float p = __expf(s[c][r]) * wv;
                lsum[r] += p;
                Ps[w][(kq << 2) + r][(c << 4) + ml] = f2b(p);
            }
        }
        // PV: A = P (per-wave LDS transpose), B = Vt rows (dv)
        const bf16x8 pa0 = *(const bf16x8*)&Ps[w][ml][kq * 8];
        const bf16x8 pa1 = *(const bf16x8*)&Ps[w][ml][32 + kq * 8];
#pragma unroll
        for (int c = 0; c < 4; c++) {
            bf16x8 v0 = *(const bf16x8*)&Vts[buf][(c << 4) + ml][kq * 8];
            bf16x8 v1 = *(const bf16x8*)&Vts[buf][(c << 4) + ml][32 + kq * 8];
            O[c] = __builtin_amdgcn_mfma_f32_16x16x32_bf16(pa0, v0, O[c], 0, 0, 0);
            O[c] = __builtin_amdgcn_mfma_f32_16x16x32_bf16(pa1, v1, O[c], 0, 0, 0);
        }

        if (pf) {  // write-late staging into the other buffer
            const int nb = buf ^ 1;
            *(bf16x8*)&Ks[nb][sr][sc]      = rk0;
            *(bf16x8*)&Ks[nb][sr][sc + 8]  = rk1;
            *(bf16x8*)&Vts[nb][sr][sc]     = rv0;
            *(bf16x8*)&Vts[nb][sr][sc + 8] = rv1;
            *(f16x8*)&Ws[nb][sr][sc]       = rw0;
            *(f16x8*)&Ws[nb][sr][sc + 8]   = rw1;
        }
        __syncthreads();
        buf ^= 1;
    }

#pragma unroll
    for (int r = 0; r < 4; r++) {
        float v = lsum[r];
        v += __shfl_xor(v, 1); v += __shfl_xor(v, 2);
        v += __shfl_xor(v, 4); v += __shfl_xor(v, 8);
        lsum[r] = 1.0f / v;
    }
    const int rowb = q0 + (w << 4) + (kq << 2);
    const int colb = (h << 6) + ml;
#pragma unroll
    for (int c = 0; c < 4; c++)
#pragma unroll
        for (int r = 0; r < 4; r++)
            Y[((long)(rowb + r) << 10) + colb + (c << 4)] = f2b(O[c][r] * lsum[r]);
}

extern "C" void kernel_launch(void* const* d_in, const int* in_sizes, int n_in,
                              void* d_out, int out_size, void* d_ws, size_t ws_size,
                              hipStream_t stream) {
    const float* x  = (const float*)d_in[0];
    const float* pe = (const float*)d_in[1];
    const float* Wq = (const float*)d_in[2];
    const float* bq = (const float*)d_in[3];
    const float* Wk = (const float*)d_in[4];
    const float* bk = (const float*)d_in[5];
    const float* Wv = (const float*)d_in[6];
    const float* bv = (const float*)d_in[7];
    const float* Wg = (const float*)d_in[8];
    const float* bg = (const float*)d_in[9];
    const float* Wy = (const float*)d_in[10];
    const float* by = (const float*)d_in[11];

    char* ws = (char*)d_ws;
    f16_t*  Wf = (f16_t*)ws;                         // 32 MB
    bf16_t* Qb = (bf16_t*)(ws + (32ul << 20));       // 2 MB
    bf16_t* Kb = (bf16_t*)(ws + (34ul << 20));       // 2 MB
    bf16_t* Vb = (bf16_t*)(ws + (36ul << 20));       // 2 MB
    bf16_t* Yb = (bf16_t*)(ws + (38ul << 20));       // 2 MB

    fused_g_proj_k<<<768 + 4096, 256, 0, stream>>>(pe, Wg, bg, Wf,
                                                   x, Wq, bq, Qb, Wk, bk, Kb, Wv, bv, Vb);
    attn_kernel<<<dim3(16, 16), 256, 0, stream>>>(Qb, Kb, Vb, Wf, Yb);
    gemmY_k<<<dim3(16, 16), 256, 0, stream>>>(Yb, Wy, by, (float*)d_out, x);
}